// Round 16
// baseline (527.633 us; speedup 1.0000x reference)
//
#include <hip/hip_runtime.h>

#define NN 200000
#define NE 600000
#define NG 8192
#define HD 128
#define FIN 7
#define BN_EPS 1e-5f

#define CHUNK 1024
#define NB 196          // ceil(NN / CHUNK)
#define TA 64           // nodes per k_agp2 tile (200000 = 3125*64)
#define NPG 8           // nodes per node-group in phases 2/3 (8 groups)
#define NPW 16          // nodes per wave in phase 1 (4 waves)
#define NBT (NN / TA)   // 3125 blocks per branch
#define ECAP 320        // LDS-staged csr entries per tile (mean 192, 5sigma ~262)
#define GMAX 8          // LDS pool slots per tile (tile spans ~3.6 graphs)

// ---------------- merged degree + graph-count histogram ----------------
__global__ void k_hist(const int* __restrict__ dstC, const int* __restrict__ dstS,
                       const int* __restrict__ batchC, const int* __restrict__ batchS,
                       int* __restrict__ degC, int* __restrict__ degS,
                       int* __restrict__ cntC, int* __restrict__ cntS) {
    int e = blockIdx.x * 256 + threadIdx.x;
    if (e < NE)            atomicAdd(&degC[dstC[e]], 1);
    else if (e < 2 * NE)   atomicAdd(&degS[dstS[e - NE]], 1);
    if (e < NN)                      atomicAdd(&cntC[batchC[e]], 1);
    else if (e >= NE && e < NE + NN) atomicAdd(&cntS[batchS[e - NE]], 1);
}

// ---- scan phase 1 + dinv + xs = x*dinv (padded to 8, lane7 = 0) ----
__global__ void k_scan1m(const int* __restrict__ degC, const int* __restrict__ degS,
                         int* __restrict__ bsumC, int* __restrict__ bsumS,
                         float* __restrict__ dinvC, float* __restrict__ dinvS,
                         const float* __restrict__ xC, const float* __restrict__ xS,
                         float* __restrict__ xsC, float* __restrict__ xsS) {
    __shared__ int sd[256];
    int t = threadIdx.x;
    int b = blockIdx.x;
    bool sBr = b >= NB;
    int bb = sBr ? b - NB : b;
    const int* deg = sBr ? degS : degC;
    const float* x = sBr ? xS : xC;
    float* dinv = sBr ? dinvS : dinvC;
    float* xs   = sBr ? xsS : xsC;
    int* bsum = sBr ? bsumS : bsumC;
    int base = bb * CHUNK + t * 4;
    int s = 0;
#pragma unroll
    for (int j = 0; j < 4; j++) {
        int i = base + j;
        if (i < NN) {
            int d = deg[i];
            s += d;
            float di = rsqrtf((float)(d + 1));
            dinv[i] = di;
            float4 v0, v1;
            v0.x = x[(size_t)i * FIN + 0] * di;
            v0.y = x[(size_t)i * FIN + 1] * di;
            v0.z = x[(size_t)i * FIN + 2] * di;
            v0.w = x[(size_t)i * FIN + 3] * di;
            v1.x = x[(size_t)i * FIN + 4] * di;
            v1.y = x[(size_t)i * FIN + 5] * di;
            v1.z = x[(size_t)i * FIN + 6] * di;
            v1.w = 0.f;
            *reinterpret_cast<float4*>(&xs[(size_t)i * 8])     = v0;
            *reinterpret_cast<float4*>(&xs[(size_t)i * 8 + 4]) = v1;
        }
    }
    sd[t] = s; __syncthreads();
    for (int st = 128; st > 0; st >>= 1) { if (t < st) sd[t] += sd[t + st]; __syncthreads(); }
    if (t == 0) bsum[bb] = sd[0];
}

__global__ void k_scan2m(int* __restrict__ bsumC, int* __restrict__ bsumS) {
    __shared__ int sd[256];
    int* bsum = blockIdx.x ? bsumS : bsumC;
    int t = threadIdx.x;
    int v = (t < NB) ? bsum[t] : 0;
    sd[t] = v; __syncthreads();
    for (int st = 1; st < 256; st <<= 1) {
        int add = (t >= st) ? sd[t - st] : 0;
        __syncthreads();
        sd[t] += add;
        __syncthreads();
    }
    if (t < NB) bsum[t] = sd[t] - v;   // exclusive
}

__global__ void k_scan3m(const int* __restrict__ degC, const int* __restrict__ degS,
                         const int* __restrict__ bsumC, const int* __restrict__ bsumS,
                         int* __restrict__ offsC, int* __restrict__ offsS,
                         int* __restrict__ curC, int* __restrict__ curS) {
    __shared__ int sd[256];
    int t = threadIdx.x;
    int b = blockIdx.x;
    bool sBr = b >= NB;
    int bb = sBr ? b - NB : b;
    const int* deg  = sBr ? degS  : degC;
    const int* bsum = sBr ? bsumS : bsumC;
    int* offs   = sBr ? offsS : offsC;
    int* cursor = sBr ? curS  : curC;
    int base = bb * CHUNK + t * 4;
    int v[4]; int s = 0;
#pragma unroll
    for (int j = 0; j < 4; j++) { int i = base + j; v[j] = (i < NN) ? deg[i] : 0; s += v[j]; }
    sd[t] = s; __syncthreads();
    for (int st = 1; st < 256; st <<= 1) {
        int add = (t >= st) ? sd[t - st] : 0;
        __syncthreads();
        sd[t] += add;
        __syncthreads();
    }
    int run = bsum[bb] + sd[t] - s;
#pragma unroll
    for (int j = 0; j < 4; j++) {
        int i = base + j;
        if (i < NN) { offs[i] = run; cursor[i] = run; run += v[j]; }
    }
    if (bb == 0 && t == 0) offs[NN] = NE;
}

// ---------------- simple CSR fill ----------------
__global__ void k_fillm(const int* __restrict__ srcC, const int* __restrict__ dstC,
                        const int* __restrict__ srcS, const int* __restrict__ dstS,
                        int* __restrict__ curC, int* __restrict__ curS,
                        int* __restrict__ csrC, int* __restrict__ csrS) {
    int e = blockIdx.x * 256 + threadIdx.x;
    if (e < NE) {
        int d = dstC[e];
        int pos = atomicAdd(&curC[d], 1);
        csrC[pos] = srcC[e];
    } else if (e < 2 * NE) {
        int ee = e - NE;
        int d = dstS[ee];
        int pos = atomicAdd(&curS[d], 1);
        csrS[pos] = srcS[ee];
    }
}

// ---------------- layer-1 aggregation -> axd rows: [ax0..ax6, dinv_i] ----------------
__global__ void k_aggxm(const float* __restrict__ xsC, const float* __restrict__ xsS,
                        const float* __restrict__ dinvC, const float* __restrict__ dinvS,
                        const int* __restrict__ offsC, const int* __restrict__ offsS,
                        const int* __restrict__ csrC, const int* __restrict__ csrS,
                        float* __restrict__ axdC, float* __restrict__ axdS) {
    int gid = blockIdx.x * 256 + threadIdx.x;    // 2*NN*8 threads (12500 blocks exact)
    bool sBr = gid >= NN * 8;
    int lid = sBr ? gid - NN * 8 : gid;
    const float* xs   = sBr ? xsS   : xsC;
    const float* dinv = sBr ? dinvS : dinvC;
    const int*   offs = sBr ? offsS : offsC;
    const int*   csr  = sBr ? csrS  : csrC;
    float*       axd  = sBr ? axdS  : axdC;
    int i = lid >> 3, f = lid & 7;
    float v = xs[lid];
    int o1 = offs[i], o2 = offs[i + 1];
    int j = o1;
    for (; j + 2 <= o2; j += 2) {                // 2-deep pipelined
        int s0 = csr[j], s1 = csr[j + 1];
        float u0 = xs[(size_t)s0 * 8 + f];
        float u1 = xs[(size_t)s1 * 8 + f];
        v += u0; v += u1;
    }
    if (j < o2) v += xs[(size_t)csr[j] * 8 + f];
    float di = dinv[i];
    axd[lid] = (f == 7) ? di : v * di;           // lane 7 carries dinv_i
}

// ------ per-source contribution, 2 features/lane: a += relu(ax_s.W0'+c')*dinv_s ------
__device__ __forceinline__ void contrib2(float4 r0, float4 r1,
                                         const float2* wp, float2 c2, float2& a) {
    float axr[7] = { r0.x, r0.y, r0.z, r0.w, r1.x, r1.y, r1.z };
    float2 y = c2;
#pragma unroll
    for (int k = 0; k < FIN; k++) {
        y.x = fmaf(axr[k], wp[k].x, y.x);
        y.y = fmaf(axr[k], wp[k].y, y.y);
    }
    a.x = fmaf(fmaxf(y.x, 0.f), r1.w, a.x);
    a.y = fmaf(fmaxf(y.y, 0.f), r1.w, a.y);
}

// phase-1 gather: wave-uniform (64 lanes = 1 edge, 2 features/lane), scalarized loop.
#define PHASE1(GETIDX)                                                                     \
    for (int n = 0; n < NPW; n++) {                                                        \
        int ln = (wv << 4) + n;                                                            \
        float2 a = make_float2(0.f, 0.f);                                                  \
        int e  = __builtin_amdgcn_readfirstlane(soffs[ln]);                                \
        int ee = __builtin_amdgcn_readfirstlane(soffs[ln + 1]);                            \
        const float4* rp = reinterpret_cast<const float4*>(&axd[(size_t)(nbase + ln) * 8]);\
        float4 p0 = rp[0], p1 = rp[1];                                                     \
        if (lane == 0) sdv_l[ln] = p1.w;                                                   \
        for (; e < ee; e++) {                                                              \
            int s = (GETIDX);                                                              \
            s = __builtin_amdgcn_readfirstlane(s);                                         \
            const float4* qp = reinterpret_cast<const float4*>(&axd[(size_t)s * 8]);       \
            float4 q0 = qp[0], q1 = qp[1];                                                 \
            contrib2(p0, p1, wp2, c2, a);                                                  \
            p0 = q0; p1 = q1;                                                              \
        }                                                                                  \
        contrib2(p0, p1, wp2, c2, a);                                                      \
        *reinterpret_cast<float2*>(&g2[ln][f2]) = a;                                       \
    }

// ---------------- fused: recompute-gather -> LDS, GEMM W1, BN+ReLU, LDS-staged pool ----
__global__ __launch_bounds__(256, 4) void k_agp2(
    const float* __restrict__ axdC, const float* __restrict__ axdS,
    const int* __restrict__ offsC, const int* __restrict__ offsS,
    const int* __restrict__ csrC, const int* __restrict__ csrS,
    const int* __restrict__ batchC, const int* __restrict__ batchS,
    const float* __restrict__ Wc0, const float* __restrict__ bc0,
    const float* __restrict__ bncG, const float* __restrict__ bncB,
    const float* __restrict__ bncM, const float* __restrict__ bncV,
    const float* __restrict__ Wc1, const float* __restrict__ bc1,
    const float* __restrict__ Ws0, const float* __restrict__ bs0,
    const float* __restrict__ bnsG, const float* __restrict__ bnsB,
    const float* __restrict__ bnsM, const float* __restrict__ bnsV,
    const float* __restrict__ Ws1, const float* __restrict__ bs1,
    float* __restrict__ poolC, float* __restrict__ poolS)
{
    __shared__ float g2[TA][HD];                 // 32 KB, unpadded (broadcast reads)
    __shared__ float spool[GMAX * HD];           // 4 KB per-graph staging
    __shared__ float sdv_l[TA];
    __shared__ int soffs[TA + 1];
    __shared__ int scsr[ECAP];
    int b = blockIdx.x;
    bool sBr = b >= NBT;
    int bb = sBr ? b - NBT : b;
    const float* axd  = sBr ? axdS  : axdC;
    const int*  offs  = sBr ? offsS : offsC;
    const int*  csr   = sBr ? csrS  : csrC;
    const int*  batch = sBr ? batchS : batchC;
    const float* W0   = sBr ? Ws0 : Wc0;
    const float* b0   = sBr ? bs0 : bc0;
    const float* bnG  = sBr ? bnsG : bncG;
    const float* bnB  = sBr ? bnsB : bncB;
    const float* bnM  = sBr ? bnsM : bncM;
    const float* bnV  = sBr ? bnsV : bncV;
    const float* W1   = sBr ? Ws1 : Wc1;
    const float* b1   = sBr ? bs1 : bc1;
    float* pool       = sBr ? poolS : poolC;

    int t = threadIdx.x;
    int nbase = bb * TA;
    if (t <= TA) soffs[t] = offs[nbase + t];
#pragma unroll
    for (int r = 0; r < GMAX * HD / 256; r++) spool[r * 256 + t] = 0.f;
    __syncthreads();
    int E0 = __builtin_amdgcn_readfirstlane(soffs[0]);
    int E1 = __builtin_amdgcn_readfirstlane(soffs[TA]);
    int Et = E1 - E0;
    int ecap = Et < ECAP ? Et : ECAP;
    for (int j = t; j < ecap; j += 256) scsr[j] = csr[E0 + j];

    int lane = t & 63, wv = t >> 6;              // phase-1 mapping: wave-uniform
    int f2 = lane * 2;

    // ---- fold BN1 into W0' (wp2) and c' (c2) for this lane's 2 columns ----
    float2 gmv = *reinterpret_cast<const float2*>(&bnG[f2]);
    float2 vrv = *reinterpret_cast<const float2*>(&bnV[f2]);
    float2 mnv = *reinterpret_cast<const float2*>(&bnM[f2]);
    float2 btv = *reinterpret_cast<const float2*>(&bnB[f2]);
    float2 b0v = *reinterpret_cast<const float2*>(&b0[f2]);
    float gx = gmv.x * rsqrtf(vrv.x + BN_EPS);
    float gy = gmv.y * rsqrtf(vrv.y + BN_EPS);
    float2 wp2[FIN];
#pragma unroll
    for (int k = 0; k < FIN; k++) {
        float2 w = *reinterpret_cast<const float2*>(&W0[k * HD + f2]);
        wp2[k] = make_float2(w.x * gx, w.y * gy);
    }
    float2 c2 = make_float2((b0v.x - mnv.x) * gx + btv.x,
                            (b0v.y - mnv.y) * gy + btv.y);
    __syncthreads();                             // scsr ready

    // ---- phase 1: wave-uniform recompute-gather, unswitched + prefetch pipelined ----
    if (Et <= ECAP) {
        PHASE1(scsr[e - E0])
    } else {
        PHASE1(((e - E0) < ECAP) ? scsr[e - E0] : csr[e])
    }
    __syncthreads();

    // ---- phase 2: GEMM (64x128 @ 128x128), thread = 8 nodes x 4 features ----
    int q = t & 31, ng = t >> 5;
    int f4 = q * 4, n0 = ng * NPG;
    float acc[NPG][4];
#pragma unroll
    for (int a = 0; a < NPG; a++)
#pragma unroll
        for (int c = 0; c < 4; c++) acc[a][c] = 0.f;

    for (int k = 0; k < 128; k += 4) {
        float ha[NPG][4];
#pragma unroll
        for (int a = 0; a < NPG; a++) {
            float4 hv = *reinterpret_cast<const float4*>(&g2[n0 + a][k]);
            ha[a][0] = hv.x; ha[a][1] = hv.y; ha[a][2] = hv.z; ha[a][3] = hv.w;
        }
#pragma unroll
        for (int j = 0; j < 4; j++) {
            float4 w = *reinterpret_cast<const float4*>(&W1[(k + j) * HD + f4]);
#pragma unroll
            for (int a = 0; a < NPG; a++) {
                acc[a][0] = fmaf(ha[a][j], w.x, acc[a][0]);
                acc[a][1] = fmaf(ha[a][j], w.y, acc[a][1]);
                acc[a][2] = fmaf(ha[a][j], w.z, acc[a][2]);
                acc[a][3] = fmaf(ha[a][j], w.w, acc[a][3]);
            }
        }
    }

    // ---- phase 3: scale by dinv_i, BN2 + ReLU, segmented accumulate into LDS slots ----
    float4 gm2 = *reinterpret_cast<const float4*>(&bnG[HD + f4]);
    float4 bt2 = *reinterpret_cast<const float4*>(&bnB[HD + f4]);
    float4 mn2 = *reinterpret_cast<const float4*>(&bnM[HD + f4]);
    float4 vr2 = *reinterpret_cast<const float4*>(&bnV[HD + f4]);
    float4 bb1 = *reinterpret_cast<const float4*>(&b1[f4]);
    float Ax = gm2.x * rsqrtf(vr2.x + BN_EPS), Bx = (bb1.x - mn2.x) * Ax + bt2.x;
    float Ay = gm2.y * rsqrtf(vr2.y + BN_EPS), By = (bb1.y - mn2.y) * Ay + bt2.y;
    float Az = gm2.z * rsqrtf(vr2.z + BN_EPS), Bz = (bb1.z - mn2.z) * Az + bt2.z;
    float Aw = gm2.w * rsqrtf(vr2.w + BN_EPS), Bw = (bb1.w - mn2.w) * Aw + bt2.w;

    int gfirst = batch[nbase];
    float sx = 0, sy = 0, sz = 0, sw = 0;
    int curg = -1;
#pragma unroll
    for (int a = 0; a < NPG; a++) {
        int i = nbase + n0 + a;
        int g = batch[i];
        float sdv = sdv_l[n0 + a];
        float zx = fmaxf(fmaf(acc[a][0] * sdv, Ax, Bx), 0.f);
        float zy = fmaxf(fmaf(acc[a][1] * sdv, Ay, By), 0.f);
        float zz = fmaxf(fmaf(acc[a][2] * sdv, Az, Bz), 0.f);
        float zw = fmaxf(fmaf(acc[a][3] * sdv, Aw, Bw), 0.f);
        if (g != curg) {
            if (curg >= 0) {
                int slot = curg - gfirst;
                if (slot < GMAX) {
                    atomicAdd(&spool[slot * HD + f4 + 0], sx);
                    atomicAdd(&spool[slot * HD + f4 + 1], sy);
                    atomicAdd(&spool[slot * HD + f4 + 2], sz);
                    atomicAdd(&spool[slot * HD + f4 + 3], sw);
                } else {
                    atomicAdd(&pool[(size_t)curg * HD + f4 + 0], sx);
                    atomicAdd(&pool[(size_t)curg * HD + f4 + 1], sy);
                    atomicAdd(&pool[(size_t)curg * HD + f4 + 2], sz);
                    atomicAdd(&pool[(size_t)curg * HD + f4 + 3], sw);
                }
            }
            curg = g; sx = zx; sy = zy; sz = zz; sw = zw;
        } else { sx += zx; sy += zy; sz += zz; sw += zw; }
    }
    {
        int slot = curg - gfirst;
        if (slot < GMAX) {
            atomicAdd(&spool[slot * HD + f4 + 0], sx);
            atomicAdd(&spool[slot * HD + f4 + 1], sy);
            atomicAdd(&spool[slot * HD + f4 + 2], sz);
            atomicAdd(&spool[slot * HD + f4 + 3], sw);
        } else {
            atomicAdd(&pool[(size_t)curg * HD + f4 + 0], sx);
            atomicAdd(&pool[(size_t)curg * HD + f4 + 1], sy);
            atomicAdd(&pool[(size_t)curg * HD + f4 + 2], sz);
            atomicAdd(&pool[(size_t)curg * HD + f4 + 3], sw);
        }
    }
    __syncthreads();

    // ---- phase 4: one coalesced atomic flush per (graph, feature) ----
    int glast = batch[nbase + TA - 1];
    int nslots = glast - gfirst + 1;
    if (nslots > GMAX) nslots = GMAX;
    for (int idx = t; idx < (nslots << 7); idx += 256) {
        atomicAdd(&pool[(size_t)(gfirst + (idx >> 7)) * HD + (idx & 127)], spool[idx]);
    }
}

// ---------------- final MLP, 8 graphs per block ----------------
#define GPB 8
__global__ __launch_bounds__(128) void k_mlp(
    const float* __restrict__ pc, const float* __restrict__ ps,
    const int* __restrict__ cc, const int* __restrict__ cs,
    const float* __restrict__ w1, const float* __restrict__ b1,
    const float* __restrict__ w2, const float* __restrict__ b2,
    float* __restrict__ outp)
{
    __shared__ float xc[GPB][256];
    __shared__ float hb[GPB][128];
    int t = threadIdx.x;
    int g0 = blockIdx.x * GPB;
#pragma unroll
    for (int gg = 0; gg < GPB; gg++) {
        int g = g0 + gg;
        xc[gg][t]       = pc[g * HD + t] / fmaxf((float)cc[g], 1.f);
        xc[gg][128 + t] = ps[g * HD + t] / fmaxf((float)cs[g], 1.f);
    }
    __syncthreads();
    float acc[GPB];
#pragma unroll
    for (int gg = 0; gg < GPB; gg++) acc[gg] = b1[t];
#pragma unroll 2
    for (int k = 0; k < 256; k++) {
        float w = w1[k * HD + t];
#pragma unroll
        for (int gg = 0; gg < GPB; gg++) acc[gg] = fmaf(xc[gg][k], w, acc[gg]);
    }
#pragma unroll
    for (int gg = 0; gg < GPB; gg++) hb[gg][t] = fmaxf(acc[gg], 0.f);
    __syncthreads();
    if (t < GPB * 2) {
        int gg = t >> 1, o = t & 1;
        float v = b2[o];
        for (int k = 0; k < 128; k++) v = fmaf(hb[gg][k], w2[k * 2 + o], v);
        outp[(size_t)(g0 + gg) * 2 + o] = v;
    }
}

extern "C" void kernel_launch(void* const* d_in, const int* in_sizes, int n_in,
                              void* d_out, int out_size, void* d_ws, size_t ws_size,
                              hipStream_t stream) {
    const float* x_c      = (const float*)d_in[0];
    const int*   ei_c     = (const int*)  d_in[1];
    const int*   batch_c  = (const int*)  d_in[2];
    const float* x_s      = (const float*)d_in[3];
    const int*   ei_s     = (const int*)  d_in[4];
    const int*   batch_s  = (const int*)  d_in[5];
    const float* Wc0      = (const float*)d_in[6];
    const float* bc0      = (const float*)d_in[7];
    const float* Wc1      = (const float*)d_in[8];
    const float* bc1      = (const float*)d_in[9];
    const float* bnc_g    = (const float*)d_in[10];
    const float* bnc_b    = (const float*)d_in[11];
    const float* bnc_m    = (const float*)d_in[12];
    const float* bnc_v    = (const float*)d_in[13];
    const float* Ws0      = (const float*)d_in[14];
    const float* bs0      = (const float*)d_in[15];
    const float* Ws1      = (const float*)d_in[16];
    const float* bs1      = (const float*)d_in[17];
    const float* bns_g    = (const float*)d_in[18];
    const float* bns_b    = (const float*)d_in[19];
    const float* bns_m    = (const float*)d_in[20];
    const float* bns_v    = (const float*)d_in[21];
    const float* fc1_w    = (const float*)d_in[22];
    const float* fc1_b    = (const float*)d_in[23];
    const float* fc2_w    = (const float*)d_in[24];
    const float* fc2_b    = (const float*)d_in[25];

    char* p = (char*)d_ws;
    auto take = [&](size_t bytes) {
        void* r = (void*)p;
        p += (bytes + 255) & ~(size_t)255;
        return r;
    };
    float* xs_c   = (float*)take((size_t)NN * 8 * 4);
    float* xs_s   = (float*)take((size_t)NN * 8 * 4);
    float* axd_c  = (float*)take((size_t)NN * 8 * 4);
    float* axd_s  = (float*)take((size_t)NN * 8 * 4);
    int*   deg_c  = (int*)  take((size_t)NN * 4);          // contiguous with deg_s (one memset)
    int*   deg_s  = (int*)  take((size_t)NN * 4);
    float* dinv_c = (float*)take((size_t)NN * 4);
    float* dinv_s = (float*)take((size_t)NN * 4);
    int*   offs_c = (int*)  take((size_t)(NN + 1) * 4);
    int*   offs_s = (int*)  take((size_t)(NN + 1) * 4);
    int*   cur_c  = (int*)  take((size_t)NN * 4);
    int*   cur_s  = (int*)  take((size_t)NN * 4);
    int*   csr_c  = (int*)  take((size_t)NE * 4);
    int*   csr_s  = (int*)  take((size_t)NE * 4);
    int*   bsum_c = (int*)  take((size_t)NB * 4);
    int*   bsum_s = (int*)  take((size_t)NB * 4);
    float* pool_c = (float*)take((size_t)NG * HD * 4);     // contiguous region: pool_c..cnt_s
    float* pool_s = (float*)take((size_t)NG * HD * 4);
    int*   cnt_c  = (int*)  take((size_t)NG * 4);
    int*   cnt_s  = (int*)  take((size_t)NG * 4);
    (void)ws_size; (void)in_sizes; (void)n_in; (void)out_size;

    hipMemsetAsync(deg_c, 0, (size_t)2 * NN * 4, stream);                       // deg_c + deg_s
    hipMemsetAsync(pool_c, 0, ((size_t)2 * NG * HD + 2 * NG) * 4, stream);      // pools + cnts

    const int* src_c = ei_c;           const int* dst_c = ei_c + NE;
    const int* src_s = ei_s;           const int* dst_s = ei_s + NE;

    k_hist  <<<(2 * NE + 255) / 256, 256, 0, stream>>>(dst_c, dst_s, batch_c, batch_s,
                                                       deg_c, deg_s, cnt_c, cnt_s);
    k_scan1m<<<2 * NB, 256, 0, stream>>>(deg_c, deg_s, bsum_c, bsum_s, dinv_c, dinv_s,
                                         x_c, x_s, xs_c, xs_s);
    k_scan2m<<<2, 256, 0, stream>>>(bsum_c, bsum_s);
    k_scan3m<<<2 * NB, 256, 0, stream>>>(deg_c, deg_s, bsum_c, bsum_s,
                                         offs_c, offs_s, cur_c, cur_s);
    k_fillm <<<(2 * NE + 255) / 256, 256, 0, stream>>>(src_c, dst_c, src_s, dst_s,
                                                       cur_c, cur_s, csr_c, csr_s);
    k_aggxm <<<2 * NN * 8 / 256, 256, 0, stream>>>(xs_c, xs_s, dinv_c, dinv_s,
                                                   offs_c, offs_s, csr_c, csr_s, axd_c, axd_s);

    k_agp2<<<2 * NBT, 256, 0, stream>>>(axd_c, axd_s,
                                        offs_c, offs_s, csr_c, csr_s, batch_c, batch_s,
                                        Wc0, bc0, bnc_g, bnc_b, bnc_m, bnc_v, Wc1, bc1,
                                        Ws0, bs0, bns_g, bns_b, bns_m, bns_v, Ws1, bs1,
                                        pool_c, pool_s);

    k_mlp<<<NG / GPB, 128, 0, stream>>>(pool_c, pool_s, cnt_c, cnt_s,
                                        fc1_w, fc1_b, fc2_w, fc2_b, (float*)d_out);
}

// Round 17
// 512.137 us; speedup vs baseline: 1.0303x; 1.0303x over previous
//
#include <hip/hip_runtime.h>

#define NN 200000
#define NE 600000
#define NG 8192
#define HD 128
#define FIN 7
#define BN_EPS 1e-5f

#define CHUNK 1024
#define NB 196          // ceil(NN / CHUNK)
#define TA 64           // nodes per k_agp2 tile (200000 = 3125*64)
#define NPG 8           // nodes per node-group (8 groups of 32 threads)
#define NBT (NN / TA)   // 3125 blocks per branch
#define ECAP 320        // LDS-staged csr entries per tile (mean 192, 5sigma ~262)
#define GMAX 8          // LDS pool slots per tile (tile spans ~3.6 graphs)

// ---------------- merged degree + graph-count histogram ----------------
__global__ void k_hist(const int* __restrict__ dstC, const int* __restrict__ dstS,
                       const int* __restrict__ batchC, const int* __restrict__ batchS,
                       int* __restrict__ degC, int* __restrict__ degS,
                       int* __restrict__ cntC, int* __restrict__ cntS) {
    int e = blockIdx.x * 256 + threadIdx.x;
    if (e < NE)            atomicAdd(&degC[dstC[e]], 1);
    else if (e < 2 * NE)   atomicAdd(&degS[dstS[e - NE]], 1);
    if (e < NN)                      atomicAdd(&cntC[batchC[e]], 1);
    else if (e >= NE && e < NE + NN) atomicAdd(&cntS[batchS[e - NE]], 1);
}

// ---- scan phase 1 + dinv + xs = x*dinv (padded to 8, lane7 = 0) ----
__global__ void k_scan1m(const int* __restrict__ degC, const int* __restrict__ degS,
                         int* __restrict__ bsumC, int* __restrict__ bsumS,
                         float* __restrict__ dinvC, float* __restrict__ dinvS,
                         const float* __restrict__ xC, const float* __restrict__ xS,
                         float* __restrict__ xsC, float* __restrict__ xsS) {
    __shared__ int sd[256];
    int t = threadIdx.x;
    int b = blockIdx.x;
    bool sBr = b >= NB;
    int bb = sBr ? b - NB : b;
    const int* deg = sBr ? degS : degC;
    const float* x = sBr ? xS : xC;
    float* dinv = sBr ? dinvS : dinvC;
    float* xs   = sBr ? xsS : xsC;
    int* bsum = sBr ? bsumS : bsumC;
    int base = bb * CHUNK + t * 4;
    int s = 0;
#pragma unroll
    for (int j = 0; j < 4; j++) {
        int i = base + j;
        if (i < NN) {
            int d = deg[i];
            s += d;
            float di = rsqrtf((float)(d + 1));
            dinv[i] = di;
            float4 v0, v1;
            v0.x = x[(size_t)i * FIN + 0] * di;
            v0.y = x[(size_t)i * FIN + 1] * di;
            v0.z = x[(size_t)i * FIN + 2] * di;
            v0.w = x[(size_t)i * FIN + 3] * di;
            v1.x = x[(size_t)i * FIN + 4] * di;
            v1.y = x[(size_t)i * FIN + 5] * di;
            v1.z = x[(size_t)i * FIN + 6] * di;
            v1.w = 0.f;
            *reinterpret_cast<float4*>(&xs[(size_t)i * 8])     = v0;
            *reinterpret_cast<float4*>(&xs[(size_t)i * 8 + 4]) = v1;
        }
    }
    sd[t] = s; __syncthreads();
    for (int st = 128; st > 0; st >>= 1) { if (t < st) sd[t] += sd[t + st]; __syncthreads(); }
    if (t == 0) bsum[bb] = sd[0];
}

__global__ void k_scan2m(int* __restrict__ bsumC, int* __restrict__ bsumS) {
    __shared__ int sd[256];
    int* bsum = blockIdx.x ? bsumS : bsumC;
    int t = threadIdx.x;
    int v = (t < NB) ? bsum[t] : 0;
    sd[t] = v; __syncthreads();
    for (int st = 1; st < 256; st <<= 1) {
        int add = (t >= st) ? sd[t - st] : 0;
        __syncthreads();
        sd[t] += add;
        __syncthreads();
    }
    if (t < NB) bsum[t] = sd[t] - v;   // exclusive
}

__global__ void k_scan3m(const int* __restrict__ degC, const int* __restrict__ degS,
                         const int* __restrict__ bsumC, const int* __restrict__ bsumS,
                         int* __restrict__ offsC, int* __restrict__ offsS,
                         int* __restrict__ curC, int* __restrict__ curS) {
    __shared__ int sd[256];
    int t = threadIdx.x;
    int b = blockIdx.x;
    bool sBr = b >= NB;
    int bb = sBr ? b - NB : b;
    const int* deg  = sBr ? degS  : degC;
    const int* bsum = sBr ? bsumS : bsumC;
    int* offs   = sBr ? offsS : offsC;
    int* cursor = sBr ? curS  : curC;
    int base = bb * CHUNK + t * 4;
    int v[4]; int s = 0;
#pragma unroll
    for (int j = 0; j < 4; j++) { int i = base + j; v[j] = (i < NN) ? deg[i] : 0; s += v[j]; }
    sd[t] = s; __syncthreads();
    for (int st = 1; st < 256; st <<= 1) {
        int add = (t >= st) ? sd[t - st] : 0;
        __syncthreads();
        sd[t] += add;
        __syncthreads();
    }
    int run = bsum[bb] + sd[t] - s;
#pragma unroll
    for (int j = 0; j < 4; j++) {
        int i = base + j;
        if (i < NN) { offs[i] = run; cursor[i] = run; run += v[j]; }
    }
    if (bb == 0 && t == 0) offs[NN] = NE;
}

// ---------------- simple CSR fill ----------------
__global__ void k_fillm(const int* __restrict__ srcC, const int* __restrict__ dstC,
                        const int* __restrict__ srcS, const int* __restrict__ dstS,
                        int* __restrict__ curC, int* __restrict__ curS,
                        int* __restrict__ csrC, int* __restrict__ csrS) {
    int e = blockIdx.x * 256 + threadIdx.x;
    if (e < NE) {
        int d = dstC[e];
        int pos = atomicAdd(&curC[d], 1);
        csrC[pos] = srcC[e];
    } else if (e < 2 * NE) {
        int ee = e - NE;
        int d = dstS[ee];
        int pos = atomicAdd(&curS[d], 1);
        csrS[pos] = srcS[ee];
    }
}

// ---------------- layer-1 aggregation -> axd rows: [ax0..ax6, dinv_i] ----------------
__global__ void k_aggxm(const float* __restrict__ xsC, const float* __restrict__ xsS,
                        const float* __restrict__ dinvC, const float* __restrict__ dinvS,
                        const int* __restrict__ offsC, const int* __restrict__ offsS,
                        const int* __restrict__ csrC, const int* __restrict__ csrS,
                        float* __restrict__ axdC, float* __restrict__ axdS) {
    int gid = blockIdx.x * 256 + threadIdx.x;    // 2*NN*8 threads (12500 blocks exact)
    bool sBr = gid >= NN * 8;
    int lid = sBr ? gid - NN * 8 : gid;
    const float* xs   = sBr ? xsS   : xsC;
    const float* dinv = sBr ? dinvS : dinvC;
    const int*   offs = sBr ? offsS : offsC;
    const int*   csr  = sBr ? csrS  : csrC;
    float*       axd  = sBr ? axdS  : axdC;
    int i = lid >> 3, f = lid & 7;
    float v = xs[lid];
    int o1 = offs[i], o2 = offs[i + 1];
    int j = o1;
    for (; j + 2 <= o2; j += 2) {                // 2-deep pipelined
        int s0 = csr[j], s1 = csr[j + 1];
        float u0 = xs[(size_t)s0 * 8 + f];
        float u1 = xs[(size_t)s1 * 8 + f];
        v += u0; v += u1;
    }
    if (j < o2) v += xs[(size_t)csr[j] * 8 + f];
    float di = dinv[i];
    axd[lid] = (f == 7) ? di : v * di;           // lane 7 carries dinv_i
}

// ------ per-source contribution: a += relu(ax_s . W0' + c') * dinv_s (4 features) ------
__device__ __forceinline__ void src_contrib(float4 r0, float4 r1,
                                            const float4* wp, const float4 c4, float4& a) {
    float axr[7] = { r0.x, r0.y, r0.z, r0.w, r1.x, r1.y, r1.z };
    float4 y = c4;
#pragma unroll
    for (int k = 0; k < FIN; k++) {
        y.x = fmaf(axr[k], wp[k].x, y.x);
        y.y = fmaf(axr[k], wp[k].y, y.y);
        y.z = fmaf(axr[k], wp[k].z, y.z);
        y.w = fmaf(axr[k], wp[k].w, y.w);
    }
    a.x = fmaf(fmaxf(y.x, 0.f), r1.w, a.x);
    a.y = fmaf(fmaxf(y.y, 0.f), r1.w, a.y);
    a.z = fmaf(fmaxf(y.z, 0.f), r1.w, a.z);
    a.w = fmaf(fmaxf(y.w, 0.f), r1.w, a.w);
}

// ---------------- fused: recompute-gather -> LDS, GEMM W1, BN+ReLU, LDS-staged pool ----
// TA=64, LDS ~38 KB (4 blocks/CU). Phase 1: flat per-group edge stream with
// incremental owner pointer (divergence ~9% instead of ~30%, no nested loop overhead).
__global__ __launch_bounds__(256, 4) void k_agp2(
    const float* __restrict__ axdC, const float* __restrict__ axdS,
    const int* __restrict__ offsC, const int* __restrict__ offsS,
    const int* __restrict__ csrC, const int* __restrict__ csrS,
    const int* __restrict__ batchC, const int* __restrict__ batchS,
    const float* __restrict__ Wc0, const float* __restrict__ bc0,
    const float* __restrict__ bncG, const float* __restrict__ bncB,
    const float* __restrict__ bncM, const float* __restrict__ bncV,
    const float* __restrict__ Wc1, const float* __restrict__ bc1,
    const float* __restrict__ Ws0, const float* __restrict__ bs0,
    const float* __restrict__ bnsG, const float* __restrict__ bnsB,
    const float* __restrict__ bnsM, const float* __restrict__ bnsV,
    const float* __restrict__ Ws1, const float* __restrict__ bs1,
    float* __restrict__ poolC, float* __restrict__ poolS)
{
    __shared__ float g2[TA][HD];                 // 32 KB, unpadded (broadcast reads)
    __shared__ float spool[GMAX * HD];           // 4 KB per-graph staging
    __shared__ float sdv_l[TA];
    __shared__ int soffs[TA + 1];
    __shared__ int scsr[ECAP];
    int b = blockIdx.x;
    bool sBr = b >= NBT;
    int bb = sBr ? b - NBT : b;
    const float* axd  = sBr ? axdS  : axdC;
    const int*  offs  = sBr ? offsS : offsC;
    const int*  csr   = sBr ? csrS  : csrC;
    const int*  batch = sBr ? batchS : batchC;
    const float* W0   = sBr ? Ws0 : Wc0;
    const float* b0   = sBr ? bs0 : bc0;
    const float* bnG  = sBr ? bnsG : bncG;
    const float* bnB  = sBr ? bnsB : bncB;
    const float* bnM  = sBr ? bnsM : bncM;
    const float* bnV  = sBr ? bnsV : bncV;
    const float* W1   = sBr ? Ws1 : Wc1;
    const float* b1   = sBr ? bs1 : bc1;
    float* pool       = sBr ? poolS : poolC;

    int t = threadIdx.x;
    int nbase = bb * TA;
    if (t <= TA) soffs[t] = offs[nbase + t];
#pragma unroll
    for (int r = 0; r < GMAX * HD / 256; r++) spool[r * 256 + t] = 0.f;
    __syncthreads();
    int E0 = soffs[0], E1 = soffs[TA];
    int Et = E1 - E0;
    int ecap = Et < ECAP ? Et : ECAP;
    for (int j = t; j < ecap; j += 256) scsr[j] = csr[E0 + j];

    int q = t & 31, ng = t >> 5;                 // 8 node-groups x 32 feature-quads
    int f4 = q * 4, n0 = ng * NPG;               // 8 nodes per group

    // ---- fold BN1 into W0' (wp) and c' (c4) for this thread's 4 columns ----
    float4 gm = *reinterpret_cast<const float4*>(&bnG[f4]);
    float4 vr = *reinterpret_cast<const float4*>(&bnV[f4]);
    float4 mn = *reinterpret_cast<const float4*>(&bnM[f4]);
    float4 bt = *reinterpret_cast<const float4*>(&bnB[f4]);
    float4 bb0 = *reinterpret_cast<const float4*>(&b0[f4]);
    float4 gsc;
    gsc.x = gm.x * rsqrtf(vr.x + BN_EPS);
    gsc.y = gm.y * rsqrtf(vr.y + BN_EPS);
    gsc.z = gm.z * rsqrtf(vr.z + BN_EPS);
    gsc.w = gm.w * rsqrtf(vr.w + BN_EPS);
    float4 wp[FIN];
#pragma unroll
    for (int k = 0; k < FIN; k++) {
        float4 w = *reinterpret_cast<const float4*>(&W0[k * HD + f4]);
        wp[k] = make_float4(w.x * gsc.x, w.y * gsc.y, w.z * gsc.z, w.w * gsc.w);
    }
    float4 c4 = make_float4((bb0.x - mn.x) * gsc.x + bt.x,
                            (bb0.y - mn.y) * gsc.y + bt.y,
                            (bb0.z - mn.z) * gsc.z + bt.z,
                            (bb0.w - mn.w) * gsc.w + bt.w);
    __syncthreads();                             // scsr ready

    // ---- phase 1: flat edge-stream recompute-gather ----
    auto init_node = [&](int ln, float4& a) {
        const float4* rp = reinterpret_cast<const float4*>(&axd[(size_t)(nbase + ln) * 8]);
        float4 r0 = rp[0], r1 = rp[1];
        if (q == 0) sdv_l[ln] = r1.w;
        a = make_float4(0.f, 0.f, 0.f, 0.f);
        src_contrib(r0, r1, wp, c4, a);
    };
    auto run_phase1 = [&](auto getidx) {
        int lo = n0;
        float4 a;
        init_node(lo, a);
        int nextoff = soffs[lo + 1];
        int gE1 = soffs[n0 + NPG];
        int e = soffs[n0];
        if (e < gE1) {
            int s = getidx(e);
            const float4* pp = reinterpret_cast<const float4*>(&axd[(size_t)s * 8]);
            float4 p0 = pp[0], p1 = pp[1];
            for (; e + 1 < gE1; e++) {
                int sn = getidx(e + 1);
                const float4* qp = reinterpret_cast<const float4*>(&axd[(size_t)sn * 8]);
                float4 q0 = qp[0], q1 = qp[1];
                while (e >= nextoff) {           // advance owner node (rare)
                    *reinterpret_cast<float4*>(&g2[lo][f4]) = a;
                    ++lo;
                    init_node(lo, a);
                    nextoff = soffs[lo + 1];
                }
                src_contrib(p0, p1, wp, c4, a);
                p0 = q0; p1 = q1;
            }
            while (e >= nextoff) {               // owner of the final edge
                *reinterpret_cast<float4*>(&g2[lo][f4]) = a;
                ++lo;
                init_node(lo, a);
                nextoff = soffs[lo + 1];
            }
            src_contrib(p0, p1, wp, c4, a);
        }
        for (;;) {                               // drain remaining nodes (self-only tail)
            *reinterpret_cast<float4*>(&g2[lo][f4]) = a;
            if (++lo >= n0 + NPG) break;
            init_node(lo, a);
        }
    };
    if (Et <= ECAP) {
        run_phase1([&](int e) { return scsr[e - E0]; });
    } else {
        run_phase1([&](int e) { int j = e - E0; return j < ECAP ? scsr[j] : csr[e]; });
    }
    __syncthreads();

    // ---- phase 2: GEMM (64x128 @ 128x128), thread = 8 nodes x 4 features ----
    float acc[NPG][4];
#pragma unroll
    for (int a = 0; a < NPG; a++)
#pragma unroll
        for (int c = 0; c < 4; c++) acc[a][c] = 0.f;

    for (int k = 0; k < 128; k += 4) {
        float ha[NPG][4];
#pragma unroll
        for (int a = 0; a < NPG; a++) {
            float4 hv = *reinterpret_cast<const float4*>(&g2[n0 + a][k]);
            ha[a][0] = hv.x; ha[a][1] = hv.y; ha[a][2] = hv.z; ha[a][3] = hv.w;
        }
#pragma unroll
        for (int j = 0; j < 4; j++) {
            float4 w = *reinterpret_cast<const float4*>(&W1[(k + j) * HD + f4]);
#pragma unroll
            for (int a = 0; a < NPG; a++) {
                acc[a][0] = fmaf(ha[a][j], w.x, acc[a][0]);
                acc[a][1] = fmaf(ha[a][j], w.y, acc[a][1]);
                acc[a][2] = fmaf(ha[a][j], w.z, acc[a][2]);
                acc[a][3] = fmaf(ha[a][j], w.w, acc[a][3]);
            }
        }
    }

    // ---- phase 3: scale by dinv_i, BN2 + ReLU, segmented accumulate into LDS slots ----
    float4 gm2 = *reinterpret_cast<const float4*>(&bnG[HD + f4]);
    float4 bt2 = *reinterpret_cast<const float4*>(&bnB[HD + f4]);
    float4 mn2 = *reinterpret_cast<const float4*>(&bnM[HD + f4]);
    float4 vr2 = *reinterpret_cast<const float4*>(&bnV[HD + f4]);
    float4 bb1 = *reinterpret_cast<const float4*>(&b1[f4]);
    float Ax = gm2.x * rsqrtf(vr2.x + BN_EPS), Bx = (bb1.x - mn2.x) * Ax + bt2.x;
    float Ay = gm2.y * rsqrtf(vr2.y + BN_EPS), By = (bb1.y - mn2.y) * Ay + bt2.y;
    float Az = gm2.z * rsqrtf(vr2.z + BN_EPS), Bz = (bb1.z - mn2.z) * Az + bt2.z;
    float Aw = gm2.w * rsqrtf(vr2.w + BN_EPS), Bw = (bb1.w - mn2.w) * Aw + bt2.w;

    int gfirst = batch[nbase];
    float sx = 0, sy = 0, sz = 0, sw = 0;
    int curg = -1;
#pragma unroll
    for (int a = 0; a < NPG; a++) {
        int i = nbase + n0 + a;
        int g = batch[i];
        float sdv = sdv_l[n0 + a];
        float zx = fmaxf(fmaf(acc[a][0] * sdv, Ax, Bx), 0.f);
        float zy = fmaxf(fmaf(acc[a][1] * sdv, Ay, By), 0.f);
        float zz = fmaxf(fmaf(acc[a][2] * sdv, Az, Bz), 0.f);
        float zw = fmaxf(fmaf(acc[a][3] * sdv, Aw, Bw), 0.f);
        if (g != curg) {
            if (curg >= 0) {
                int slot = curg - gfirst;
                if (slot < GMAX) {
                    atomicAdd(&spool[slot * HD + f4 + 0], sx);
                    atomicAdd(&spool[slot * HD + f4 + 1], sy);
                    atomicAdd(&spool[slot * HD + f4 + 2], sz);
                    atomicAdd(&spool[slot * HD + f4 + 3], sw);
                } else {
                    atomicAdd(&pool[(size_t)curg * HD + f4 + 0], sx);
                    atomicAdd(&pool[(size_t)curg * HD + f4 + 1], sy);
                    atomicAdd(&pool[(size_t)curg * HD + f4 + 2], sz);
                    atomicAdd(&pool[(size_t)curg * HD + f4 + 3], sw);
                }
            }
            curg = g; sx = zx; sy = zy; sz = zz; sw = zw;
        } else { sx += zx; sy += zy; sz += zz; sw += zw; }
    }
    {
        int slot = curg - gfirst;
        if (slot < GMAX) {
            atomicAdd(&spool[slot * HD + f4 + 0], sx);
            atomicAdd(&spool[slot * HD + f4 + 1], sy);
            atomicAdd(&spool[slot * HD + f4 + 2], sz);
            atomicAdd(&spool[slot * HD + f4 + 3], sw);
        } else {
            atomicAdd(&pool[(size_t)curg * HD + f4 + 0], sx);
            atomicAdd(&pool[(size_t)curg * HD + f4 + 1], sy);
            atomicAdd(&pool[(size_t)curg * HD + f4 + 2], sz);
            atomicAdd(&pool[(size_t)curg * HD + f4 + 3], sw);
        }
    }
    __syncthreads();

    // ---- phase 4: one coalesced atomic flush per (graph, feature) ----
    int glast = batch[nbase + TA - 1];
    int nslots = glast - gfirst + 1;
    if (nslots > GMAX) nslots = GMAX;
    for (int idx = t; idx < (nslots << 7); idx += 256) {
        atomicAdd(&pool[(size_t)(gfirst + (idx >> 7)) * HD + (idx & 127)], spool[idx]);
    }
}

// ---------------- final MLP, 8 graphs per block ----------------
#define GPB 8
__global__ __launch_bounds__(128) void k_mlp(
    const float* __restrict__ pc, const float* __restrict__ ps,
    const int* __restrict__ cc, const int* __restrict__ cs,
    const float* __restrict__ w1, const float* __restrict__ b1,
    const float* __restrict__ w2, const float* __restrict__ b2,
    float* __restrict__ outp)
{
    __shared__ float xc[GPB][256];
    __shared__ float hb[GPB][128];
    int t = threadIdx.x;
    int g0 = blockIdx.x * GPB;
#pragma unroll
    for (int gg = 0; gg < GPB; gg++) {
        int g = g0 + gg;
        xc[gg][t]       = pc[g * HD + t] / fmaxf((float)cc[g], 1.f);
        xc[gg][128 + t] = ps[g * HD + t] / fmaxf((float)cs[g], 1.f);
    }
    __syncthreads();
    float acc[GPB];
#pragma unroll
    for (int gg = 0; gg < GPB; gg++) acc[gg] = b1[t];
#pragma unroll 2
    for (int k = 0; k < 256; k++) {
        float w = w1[k * HD + t];
#pragma unroll
        for (int gg = 0; gg < GPB; gg++) acc[gg] = fmaf(xc[gg][k], w, acc[gg]);
    }
#pragma unroll
    for (int gg = 0; gg < GPB; gg++) hb[gg][t] = fmaxf(acc[gg], 0.f);
    __syncthreads();
    if (t < GPB * 2) {
        int gg = t >> 1, o = t & 1;
        float v = b2[o];
        for (int k = 0; k < 128; k++) v = fmaf(hb[gg][k], w2[k * 2 + o], v);
        outp[(size_t)(g0 + gg) * 2 + o] = v;
    }
}

extern "C" void kernel_launch(void* const* d_in, const int* in_sizes, int n_in,
                              void* d_out, int out_size, void* d_ws, size_t ws_size,
                              hipStream_t stream) {
    const float* x_c      = (const float*)d_in[0];
    const int*   ei_c     = (const int*)  d_in[1];
    const int*   batch_c  = (const int*)  d_in[2];
    const float* x_s      = (const float*)d_in[3];
    const int*   ei_s     = (const int*)  d_in[4];
    const int*   batch_s  = (const int*)  d_in[5];
    const float* Wc0      = (const float*)d_in[6];
    const float* bc0      = (const float*)d_in[7];
    const float* Wc1      = (const float*)d_in[8];
    const float* bc1      = (const float*)d_in[9];
    const float* bnc_g    = (const float*)d_in[10];
    const float* bnc_b    = (const float*)d_in[11];
    const float* bnc_m    = (const float*)d_in[12];
    const float* bnc_v    = (const float*)d_in[13];
    const float* Ws0      = (const float*)d_in[14];
    const float* bs0      = (const float*)d_in[15];
    const float* Ws1      = (const float*)d_in[16];
    const float* bs1      = (const float*)d_in[17];
    const float* bns_g    = (const float*)d_in[18];
    const float* bns_b    = (const float*)d_in[19];
    const float* bns_m    = (const float*)d_in[20];
    const float* bns_v    = (const float*)d_in[21];
    const float* fc1_w    = (const float*)d_in[22];
    const float* fc1_b    = (const float*)d_in[23];
    const float* fc2_w    = (const float*)d_in[24];
    const float* fc2_b    = (const float*)d_in[25];

    char* p = (char*)d_ws;
    auto take = [&](size_t bytes) {
        void* r = (void*)p;
        p += (bytes + 255) & ~(size_t)255;
        return r;
    };
    float* xs_c   = (float*)take((size_t)NN * 8 * 4);
    float* xs_s   = (float*)take((size_t)NN * 8 * 4);
    float* axd_c  = (float*)take((size_t)NN * 8 * 4);
    float* axd_s  = (float*)take((size_t)NN * 8 * 4);
    int*   deg_c  = (int*)  take((size_t)NN * 4);          // contiguous with deg_s (one memset)
    int*   deg_s  = (int*)  take((size_t)NN * 4);
    float* dinv_c = (float*)take((size_t)NN * 4);
    float* dinv_s = (float*)take((size_t)NN * 4);
    int*   offs_c = (int*)  take((size_t)(NN + 1) * 4);
    int*   offs_s = (int*)  take((size_t)(NN + 1) * 4);
    int*   cur_c  = (int*)  take((size_t)NN * 4);
    int*   cur_s  = (int*)  take((size_t)NN * 4);
    int*   csr_c  = (int*)  take((size_t)NE * 4);
    int*   csr_s  = (int*)  take((size_t)NE * 4);
    int*   bsum_c = (int*)  take((size_t)NB * 4);
    int*   bsum_s = (int*)  take((size_t)NB * 4);
    float* pool_c = (float*)take((size_t)NG * HD * 4);     // contiguous region: pool_c..cnt_s
    float* pool_s = (float*)take((size_t)NG * HD * 4);
    int*   cnt_c  = (int*)  take((size_t)NG * 4);
    int*   cnt_s  = (int*)  take((size_t)NG * 4);
    (void)ws_size; (void)in_sizes; (void)n_in; (void)out_size;

    hipMemsetAsync(deg_c, 0, (size_t)2 * NN * 4, stream);                       // deg_c + deg_s
    hipMemsetAsync(pool_c, 0, ((size_t)2 * NG * HD + 2 * NG) * 4, stream);      // pools + cnts

    const int* src_c = ei_c;           const int* dst_c = ei_c + NE;
    const int* src_s = ei_s;           const int* dst_s = ei_s + NE;

    k_hist  <<<(2 * NE + 255) / 256, 256, 0, stream>>>(dst_c, dst_s, batch_c, batch_s,
                                                       deg_c, deg_s, cnt_c, cnt_s);
    k_scan1m<<<2 * NB, 256, 0, stream>>>(deg_c, deg_s, bsum_c, bsum_s, dinv_c, dinv_s,
                                         x_c, x_s, xs_c, xs_s);
    k_scan2m<<<2, 256, 0, stream>>>(bsum_c, bsum_s);
    k_scan3m<<<2 * NB, 256, 0, stream>>>(deg_c, deg_s, bsum_c, bsum_s,
                                         offs_c, offs_s, cur_c, cur_s);
    k_fillm <<<(2 * NE + 255) / 256, 256, 0, stream>>>(src_c, dst_c, src_s, dst_s,
                                                       cur_c, cur_s, csr_c, csr_s);
    k_aggxm <<<2 * NN * 8 / 256, 256, 0, stream>>>(xs_c, xs_s, dinv_c, dinv_s,
                                                   offs_c, offs_s, csr_c, csr_s, axd_c, axd_s);

    k_agp2<<<2 * NBT, 256, 0, stream>>>(axd_c, axd_s,
                                        offs_c, offs_s, csr_c, csr_s, batch_c, batch_s,
                                        Wc0, bc0, bnc_g, bnc_b, bnc_m, bnc_v, Wc1, bc1,
                                        Ws0, bs0, bns_g, bns_b, bns_m, bns_v, Ws1, bs1,
                                        pool_c, pool_s);

    k_mlp<<<NG / GPB, 128, 0, stream>>>(pool_c, pool_s, cnt_c, cnt_s,
                                        fc1_w, fc1_b, fc2_w, fc2_b, (float*)d_out);
}

// Round 18
// 442.894 us; speedup vs baseline: 1.1913x; 1.1563x over previous
//
#include <hip/hip_runtime.h>

#define NN 200000
#define NE 600000
#define NG 8192
#define HD 128
#define FIN 7
#define BN_EPS 1e-5f

#define CHUNK 1024
#define NB 196          // ceil(NN / CHUNK)
#define TA 64           // nodes per k_agp2 tile (200000 = 3125*64)
#define NPG 8           // nodes per node-group (8 groups of 32 threads)
#define NBT (NN / TA)   // 3125 blocks per branch
#define ECAP 320        // LDS-staged csr entries per tile (mean 192, 5sigma ~262)
#define GMAX 8          // LDS pool slots per tile (tile spans ~3.6 graphs)

// ---------------- degree histogram + per-edge rank + graph-count histogram ----------------
__global__ void k_hist(const int* __restrict__ dstC, const int* __restrict__ dstS,
                       const int* __restrict__ batchC, const int* __restrict__ batchS,
                       int* __restrict__ degC, int* __restrict__ degS,
                       int* __restrict__ cntC, int* __restrict__ cntS,
                       int* __restrict__ rankC, int* __restrict__ rankS) {
    int e = blockIdx.x * 256 + threadIdx.x;
    if (e < NE)            rankC[e] = atomicAdd(&degC[dstC[e]], 1);
    else if (e < 2 * NE)   rankS[e - NE] = atomicAdd(&degS[dstS[e - NE]], 1);
    if (e < NN)                      atomicAdd(&cntC[batchC[e]], 1);
    else if (e >= NE && e < NE + NN) atomicAdd(&cntS[batchS[e - NE]], 1);
}

// ---- scan phase 1 + dinv + xs = x*dinv (padded to 8, lane7 = 0) ----
__global__ void k_scan1m(const int* __restrict__ degC, const int* __restrict__ degS,
                         int* __restrict__ bsumC, int* __restrict__ bsumS,
                         float* __restrict__ dinvC, float* __restrict__ dinvS,
                         const float* __restrict__ xC, const float* __restrict__ xS,
                         float* __restrict__ xsC, float* __restrict__ xsS) {
    __shared__ int sd[256];
    int t = threadIdx.x;
    int b = blockIdx.x;
    bool sBr = b >= NB;
    int bb = sBr ? b - NB : b;
    const int* deg = sBr ? degS : degC;
    const float* x = sBr ? xS : xC;
    float* dinv = sBr ? dinvS : dinvC;
    float* xs   = sBr ? xsS : xsC;
    int* bsum = sBr ? bsumS : bsumC;
    int base = bb * CHUNK + t * 4;
    int s = 0;
#pragma unroll
    for (int j = 0; j < 4; j++) {
        int i = base + j;
        if (i < NN) {
            int d = deg[i];
            s += d;
            float di = rsqrtf((float)(d + 1));
            dinv[i] = di;
            float4 v0, v1;
            v0.x = x[(size_t)i * FIN + 0] * di;
            v0.y = x[(size_t)i * FIN + 1] * di;
            v0.z = x[(size_t)i * FIN + 2] * di;
            v0.w = x[(size_t)i * FIN + 3] * di;
            v1.x = x[(size_t)i * FIN + 4] * di;
            v1.y = x[(size_t)i * FIN + 5] * di;
            v1.z = x[(size_t)i * FIN + 6] * di;
            v1.w = 0.f;
            *reinterpret_cast<float4*>(&xs[(size_t)i * 8])     = v0;
            *reinterpret_cast<float4*>(&xs[(size_t)i * 8 + 4]) = v1;
        }
    }
    sd[t] = s; __syncthreads();
    for (int st = 128; st > 0; st >>= 1) { if (t < st) sd[t] += sd[t + st]; __syncthreads(); }
    if (t == 0) bsum[bb] = sd[0];
}

// ---- scan phase 3 with folded cross-block scan (bsum holds raw block totals) ----
__global__ void k_scan3m(const int* __restrict__ degC, const int* __restrict__ degS,
                         const int* __restrict__ bsumC, const int* __restrict__ bsumS,
                         int* __restrict__ offsC, int* __restrict__ offsS) {
    __shared__ int sd[256];
    __shared__ int sb[256];
    int t = threadIdx.x;
    int b = blockIdx.x;
    bool sBr = b >= NB;
    int bb = sBr ? b - NB : b;
    const int* deg  = sBr ? degS  : degC;
    const int* bsum = sBr ? bsumS : bsumC;
    int* offs   = sBr ? offsS : offsC;

    // cross-block exclusive prefix (redundant per-block scan of 196 totals)
    sb[t] = (t < NB) ? bsum[t] : 0;
    __syncthreads();
    for (int st = 1; st < 256; st <<= 1) {
        int add = (t >= st) ? sb[t - st] : 0;
        __syncthreads();
        sb[t] += add;
        __syncthreads();
    }
    int base0 = (bb == 0) ? 0 : sb[bb - 1];

    int base = bb * CHUNK + t * 4;
    int v[4]; int s = 0;
#pragma unroll
    for (int j = 0; j < 4; j++) { int i = base + j; v[j] = (i < NN) ? deg[i] : 0; s += v[j]; }
    sd[t] = s; __syncthreads();
    for (int st = 1; st < 256; st <<= 1) {
        int add = (t >= st) ? sd[t - st] : 0;
        __syncthreads();
        sd[t] += add;
        __syncthreads();
    }
    int run = base0 + sd[t] - s;
#pragma unroll
    for (int j = 0; j < 4; j++) {
        int i = base + j;
        if (i < NN) { offs[i] = run; run += v[j]; }
    }
    if (bb == 0 && t == 0) offs[NN] = NE;
}

// ---------------- atomic-free CSR fill via precomputed ranks ----------------
__global__ void k_fillm(const int* __restrict__ srcC, const int* __restrict__ dstC,
                        const int* __restrict__ srcS, const int* __restrict__ dstS,
                        const int* __restrict__ rankC, const int* __restrict__ rankS,
                        const int* __restrict__ offsC, const int* __restrict__ offsS,
                        int* __restrict__ csrC, int* __restrict__ csrS) {
    int e = blockIdx.x * 256 + threadIdx.x;
    if (e < NE) {
        int d = dstC[e];
        csrC[offsC[d] + rankC[e]] = srcC[e];
    } else if (e < 2 * NE) {
        int ee = e - NE;
        int d = dstS[ee];
        csrS[offsS[d] + rankS[ee]] = srcS[ee];
    }
}

// ---------------- layer-1 aggregation -> axd rows: [ax0..ax6, dinv_i] ----------------
__global__ void k_aggxm(const float* __restrict__ xsC, const float* __restrict__ xsS,
                        const float* __restrict__ dinvC, const float* __restrict__ dinvS,
                        const int* __restrict__ offsC, const int* __restrict__ offsS,
                        const int* __restrict__ csrC, const int* __restrict__ csrS,
                        float* __restrict__ axdC, float* __restrict__ axdS) {
    int gid = blockIdx.x * 256 + threadIdx.x;    // 2*NN*8 threads (12500 blocks exact)
    bool sBr = gid >= NN * 8;
    int lid = sBr ? gid - NN * 8 : gid;
    const float* xs   = sBr ? xsS   : xsC;
    const float* dinv = sBr ? dinvS : dinvC;
    const int*   offs = sBr ? offsS : offsC;
    const int*   csr  = sBr ? csrS  : csrC;
    float*       axd  = sBr ? axdS  : axdC;
    int i = lid >> 3, f = lid & 7;
    float v = xs[lid];
    int o1 = offs[i], o2 = offs[i + 1];
    int j = o1;
    for (; j + 2 <= o2; j += 2) {                // 2-deep pipelined
        int s0 = csr[j], s1 = csr[j + 1];
        float u0 = xs[(size_t)s0 * 8 + f];
        float u1 = xs[(size_t)s1 * 8 + f];
        v += u0; v += u1;
    }
    if (j < o2) v += xs[(size_t)csr[j] * 8 + f];
    float di = dinv[i];
    axd[lid] = (f == 7) ? di : v * di;           // lane 7 carries dinv_i
}

// ------ per-source contribution: a += relu(ax_s . W0' + c') * dinv_s (4 features) ------
__device__ __forceinline__ void src_contrib(float4 r0, float4 r1,
                                            const float4* wp, const float4 c4, float4& a) {
    float axr[7] = { r0.x, r0.y, r0.z, r0.w, r1.x, r1.y, r1.z };
    float4 y = c4;
#pragma unroll
    for (int k = 0; k < FIN; k++) {
        y.x = fmaf(axr[k], wp[k].x, y.x);
        y.y = fmaf(axr[k], wp[k].y, y.y);
        y.z = fmaf(axr[k], wp[k].z, y.z);
        y.w = fmaf(axr[k], wp[k].w, y.w);
    }
    a.x = fmaf(fmaxf(y.x, 0.f), r1.w, a.x);
    a.y = fmaf(fmaxf(y.y, 0.f), r1.w, a.y);
    a.z = fmaf(fmaxf(y.z, 0.f), r1.w, a.z);
    a.w = fmaf(fmaxf(y.w, 0.f), r1.w, a.w);
}

// phase-1 gather, unswitched on tile-fits-in-scsr (uniform per-block branch).
// GETIDX is the edge-source fetch expression; prefetch pipeline hides L2 latency.
#define PHASE1(GETIDX)                                                                     \
    _Pragma("unroll")                                                                      \
    for (int n = 0; n < NPG; n++) {                                                        \
        int ln = n0 + n;                                                                   \
        float4 a = make_float4(0.f, 0.f, 0.f, 0.f);                                        \
        int e = soffs[ln], ee = soffs[ln + 1];                                             \
        float4 p0 = *reinterpret_cast<const float4*>(&axd[(size_t)(nbase + ln) * 8]);      \
        float4 p1 = *reinterpret_cast<const float4*>(&axd[(size_t)(nbase + ln) * 8 + 4]);  \
        sdvN[n] = p1.w;                                                                    \
        for (; e < ee; e++) {                                                              \
            int s = (GETIDX);                                                              \
            float4 q0 = *reinterpret_cast<const float4*>(&axd[(size_t)s * 8]);             \
            float4 q1 = *reinterpret_cast<const float4*>(&axd[(size_t)s * 8 + 4]);         \
            src_contrib(p0, p1, wp, c4, a);                                                \
            p0 = q0; p1 = q1;                                                              \
        }                                                                                  \
        src_contrib(p0, p1, wp, c4, a);                                                    \
        *reinterpret_cast<float4*>(&g2[ln][f4]) = a;                                       \
    }

// ---------------- fused: recompute-gather -> LDS, GEMM W1, BN+ReLU, LDS-staged pool ----
// TA=64, LDS ~38 KB (4 blocks/CU), clean unswitched gather loop. (round-15 proven form)
__global__ __launch_bounds__(256, 4) void k_agp2(
    const float* __restrict__ axdC, const float* __restrict__ axdS,
    const int* __restrict__ offsC, const int* __restrict__ offsS,
    const int* __restrict__ csrC, const int* __restrict__ csrS,
    const int* __restrict__ batchC, const int* __restrict__ batchS,
    const float* __restrict__ Wc0, const float* __restrict__ bc0,
    const float* __restrict__ bncG, const float* __restrict__ bncB,
    const float* __restrict__ bncM, const float* __restrict__ bncV,
    const float* __restrict__ Wc1, const float* __restrict__ bc1,
    const float* __restrict__ Ws0, const float* __restrict__ bs0,
    const float* __restrict__ bnsG, const float* __restrict__ bnsB,
    const float* __restrict__ bnsM, const float* __restrict__ bnsV,
    const float* __restrict__ Ws1, const float* __restrict__ bs1,
    float* __restrict__ poolC, float* __restrict__ poolS)
{
    __shared__ float g2[TA][HD];                 // 32 KB, unpadded (broadcast reads)
    __shared__ float spool[GMAX * HD];           // 4 KB per-graph staging
    __shared__ int soffs[TA + 1];
    __shared__ int scsr[ECAP];
    int b = blockIdx.x;
    bool sBr = b >= NBT;
    int bb = sBr ? b - NBT : b;
    const float* axd  = sBr ? axdS  : axdC;
    const int*  offs  = sBr ? offsS : offsC;
    const int*  csr   = sBr ? csrS  : csrC;
    const int*  batch = sBr ? batchS : batchC;
    const float* W0   = sBr ? Ws0 : Wc0;
    const float* b0   = sBr ? bs0 : bc0;
    const float* bnG  = sBr ? bnsG : bncG;
    const float* bnB  = sBr ? bnsB : bncB;
    const float* bnM  = sBr ? bnsM : bncM;
    const float* bnV  = sBr ? bnsV : bncV;
    const float* W1   = sBr ? Ws1 : Wc1;
    const float* b1   = sBr ? bs1 : bc1;
    float* pool       = sBr ? poolS : poolC;

    int t = threadIdx.x;
    int nbase = bb * TA;
    if (t <= TA) soffs[t] = offs[nbase + t];
#pragma unroll
    for (int r = 0; r < GMAX * HD / 256; r++) spool[r * 256 + t] = 0.f;
    __syncthreads();
    int E0 = soffs[0], E1 = soffs[TA];
    int Et = E1 - E0;
    int ecap = Et < ECAP ? Et : ECAP;
    for (int j = t; j < ecap; j += 256) scsr[j] = csr[E0 + j];

    int q = t & 31, ng = t >> 5;                 // 8 node-groups x 32 feature-quads
    int f4 = q * 4, n0 = ng * NPG;               // 8 nodes per group

    // ---- fold BN1 into W0' (wp) and c' (c4) for this thread's 4 columns ----
    float4 gm = *reinterpret_cast<const float4*>(&bnG[f4]);
    float4 vr = *reinterpret_cast<const float4*>(&bnV[f4]);
    float4 mn = *reinterpret_cast<const float4*>(&bnM[f4]);
    float4 bt = *reinterpret_cast<const float4*>(&bnB[f4]);
    float4 bb0 = *reinterpret_cast<const float4*>(&b0[f4]);
    float4 gsc;
    gsc.x = gm.x * rsqrtf(vr.x + BN_EPS);
    gsc.y = gm.y * rsqrtf(vr.y + BN_EPS);
    gsc.z = gm.z * rsqrtf(vr.z + BN_EPS);
    gsc.w = gm.w * rsqrtf(vr.w + BN_EPS);
    float4 wp[FIN];
#pragma unroll
    for (int k = 0; k < FIN; k++) {
        float4 w = *reinterpret_cast<const float4*>(&W0[k * HD + f4]);
        wp[k] = make_float4(w.x * gsc.x, w.y * gsc.y, w.z * gsc.z, w.w * gsc.w);
    }
    float4 c4 = make_float4((bb0.x - mn.x) * gsc.x + bt.x,
                            (bb0.y - mn.y) * gsc.y + bt.y,
                            (bb0.z - mn.z) * gsc.z + bt.z,
                            (bb0.w - mn.w) * gsc.w + bt.w);
    __syncthreads();                             // scsr ready

    // ---- phase 1: recompute-gather, unswitched + prefetch pipelined ----
    float sdvN[NPG];
    if (Et <= ECAP) {
        PHASE1(scsr[e - E0])
    } else {
        PHASE1(((e - E0) < ECAP) ? scsr[e - E0] : csr[e])
    }
    __syncthreads();

    // ---- phase 2: GEMM (64x128 @ 128x128), thread = 8 nodes x 4 features ----
    float acc[NPG][4];
#pragma unroll
    for (int a = 0; a < NPG; a++)
#pragma unroll
        for (int c = 0; c < 4; c++) acc[a][c] = 0.f;

    for (int k = 0; k < 128; k += 4) {
        float ha[NPG][4];
#pragma unroll
        for (int a = 0; a < NPG; a++) {
            float4 hv = *reinterpret_cast<const float4*>(&g2[n0 + a][k]);
            ha[a][0] = hv.x; ha[a][1] = hv.y; ha[a][2] = hv.z; ha[a][3] = hv.w;
        }
#pragma unroll
        for (int j = 0; j < 4; j++) {
            float4 w = *reinterpret_cast<const float4*>(&W1[(k + j) * HD + f4]);
#pragma unroll
            for (int a = 0; a < NPG; a++) {
                acc[a][0] = fmaf(ha[a][j], w.x, acc[a][0]);
                acc[a][1] = fmaf(ha[a][j], w.y, acc[a][1]);
                acc[a][2] = fmaf(ha[a][j], w.z, acc[a][2]);
                acc[a][3] = fmaf(ha[a][j], w.w, acc[a][3]);
            }
        }
    }

    // ---- phase 3: scale by dinv_i, BN2 + ReLU, segmented accumulate into LDS slots ----
    float4 gm2 = *reinterpret_cast<const float4*>(&bnG[HD + f4]);
    float4 bt2 = *reinterpret_cast<const float4*>(&bnB[HD + f4]);
    float4 mn2 = *reinterpret_cast<const float4*>(&bnM[HD + f4]);
    float4 vr2 = *reinterpret_cast<const float4*>(&bnV[HD + f4]);
    float4 bb1 = *reinterpret_cast<const float4*>(&b1[f4]);
    float Ax = gm2.x * rsqrtf(vr2.x + BN_EPS), Bx = (bb1.x - mn2.x) * Ax + bt2.x;
    float Ay = gm2.y * rsqrtf(vr2.y + BN_EPS), By = (bb1.y - mn2.y) * Ay + bt2.y;
    float Az = gm2.z * rsqrtf(vr2.z + BN_EPS), Bz = (bb1.z - mn2.z) * Az + bt2.z;
    float Aw = gm2.w * rsqrtf(vr2.w + BN_EPS), Bw = (bb1.w - mn2.w) * Aw + bt2.w;

    int gfirst = batch[nbase];
    float sx = 0, sy = 0, sz = 0, sw = 0;
    int curg = -1;
#pragma unroll
    for (int a = 0; a < NPG; a++) {
        int i = nbase + n0 + a;
        int g = batch[i];
        float sdv = sdvN[a];
        float zx = fmaxf(fmaf(acc[a][0] * sdv, Ax, Bx), 0.f);
        float zy = fmaxf(fmaf(acc[a][1] * sdv, Ay, By), 0.f);
        float zz = fmaxf(fmaf(acc[a][2] * sdv, Az, Bz), 0.f);
        float zw = fmaxf(fmaf(acc[a][3] * sdv, Aw, Bw), 0.f);
        if (g != curg) {
            if (curg >= 0) {
                int slot = curg - gfirst;
                if (slot < GMAX) {
                    atomicAdd(&spool[slot * HD + f4 + 0], sx);
                    atomicAdd(&spool[slot * HD + f4 + 1], sy);
                    atomicAdd(&spool[slot * HD + f4 + 2], sz);
                    atomicAdd(&spool[slot * HD + f4 + 3], sw);
                } else {
                    atomicAdd(&pool[(size_t)curg * HD + f4 + 0], sx);
                    atomicAdd(&pool[(size_t)curg * HD + f4 + 1], sy);
                    atomicAdd(&pool[(size_t)curg * HD + f4 + 2], sz);
                    atomicAdd(&pool[(size_t)curg * HD + f4 + 3], sw);
                }
            }
            curg = g; sx = zx; sy = zy; sz = zz; sw = zw;
        } else { sx += zx; sy += zy; sz += zz; sw += zw; }
    }
    {
        int slot = curg - gfirst;
        if (slot < GMAX) {
            atomicAdd(&spool[slot * HD + f4 + 0], sx);
            atomicAdd(&spool[slot * HD + f4 + 1], sy);
            atomicAdd(&spool[slot * HD + f4 + 2], sz);
            atomicAdd(&spool[slot * HD + f4 + 3], sw);
        } else {
            atomicAdd(&pool[(size_t)curg * HD + f4 + 0], sx);
            atomicAdd(&pool[(size_t)curg * HD + f4 + 1], sy);
            atomicAdd(&pool[(size_t)curg * HD + f4 + 2], sz);
            atomicAdd(&pool[(size_t)curg * HD + f4 + 3], sw);
        }
    }
    __syncthreads();

    // ---- phase 4: one coalesced atomic flush per (graph, feature) ----
    int glast = batch[nbase + TA - 1];
    int nslots = glast - gfirst + 1;
    if (nslots > GMAX) nslots = GMAX;
    for (int idx = t; idx < (nslots << 7); idx += 256) {
        atomicAdd(&pool[(size_t)(gfirst + (idx >> 7)) * HD + (idx & 127)], spool[idx]);
    }
}

// ---------------- final MLP, 8 graphs per block ----------------
#define GPB 8
__global__ __launch_bounds__(128) void k_mlp(
    const float* __restrict__ pc, const float* __restrict__ ps,
    const int* __restrict__ cc, const int* __restrict__ cs,
    const float* __restrict__ w1, const float* __restrict__ b1,
    const float* __restrict__ w2, const float* __restrict__ b2,
    float* __restrict__ outp)
{
    __shared__ float xc[GPB][256];
    __shared__ float hb[GPB][128];
    int t = threadIdx.x;
    int g0 = blockIdx.x * GPB;
#pragma unroll
    for (int gg = 0; gg < GPB; gg++) {
        int g = g0 + gg;
        xc[gg][t]       = pc[g * HD + t] / fmaxf((float)cc[g], 1.f);
        xc[gg][128 + t] = ps[g * HD + t] / fmaxf((float)cs[g], 1.f);
    }
    __syncthreads();
    float acc[GPB];
#pragma unroll
    for (int gg = 0; gg < GPB; gg++) acc[gg] = b1[t];
#pragma unroll 2
    for (int k = 0; k < 256; k++) {
        float w = w1[k * HD + t];
#pragma unroll
        for (int gg = 0; gg < GPB; gg++) acc[gg] = fmaf(xc[gg][k], w, acc[gg]);
    }
#pragma unroll
    for (int gg = 0; gg < GPB; gg++) hb[gg][t] = fmaxf(acc[gg], 0.f);
    __syncthreads();
    if (t < GPB * 2) {
        int gg = t >> 1, o = t & 1;
        float v = b2[o];
        for (int k = 0; k < 128; k++) v = fmaf(hb[gg][k], w2[k * 2 + o], v);
        outp[(size_t)(g0 + gg) * 2 + o] = v;
    }
}

extern "C" void kernel_launch(void* const* d_in, const int* in_sizes, int n_in,
                              void* d_out, int out_size, void* d_ws, size_t ws_size,
                              hipStream_t stream) {
    const float* x_c      = (const float*)d_in[0];
    const int*   ei_c     = (const int*)  d_in[1];
    const int*   batch_c  = (const int*)  d_in[2];
    const float* x_s      = (const float*)d_in[3];
    const int*   ei_s     = (const int*)  d_in[4];
    const int*   batch_s  = (const int*)  d_in[5];
    const float* Wc0      = (const float*)d_in[6];
    const float* bc0      = (const float*)d_in[7];
    const float* Wc1      = (const float*)d_in[8];
    const float* bc1      = (const float*)d_in[9];
    const float* bnc_g    = (const float*)d_in[10];
    const float* bnc_b    = (const float*)d_in[11];
    const float* bnc_m    = (const float*)d_in[12];
    const float* bnc_v    = (const float*)d_in[13];
    const float* Ws0      = (const float*)d_in[14];
    const float* bs0      = (const float*)d_in[15];
    const float* Ws1      = (const float*)d_in[16];
    const float* bs1      = (const float*)d_in[17];
    const float* bns_g    = (const float*)d_in[18];
    const float* bns_b    = (const float*)d_in[19];
    const float* bns_m    = (const float*)d_in[20];
    const float* bns_v    = (const float*)d_in[21];
    const float* fc1_w    = (const float*)d_in[22];
    const float* fc1_b    = (const float*)d_in[23];
    const float* fc2_w    = (const float*)d_in[24];
    const float* fc2_b    = (const float*)d_in[25];

    char* p = (char*)d_ws;
    auto take = [&](size_t bytes) {
        void* r = (void*)p;
        p += (bytes + 255) & ~(size_t)255;
        return r;
    };
    float* xs_c   = (float*)take((size_t)NN * 8 * 4);
    float* xs_s   = (float*)take((size_t)NN * 8 * 4);
    float* axd_c  = (float*)take((size_t)NN * 8 * 4);
    float* axd_s  = (float*)take((size_t)NN * 8 * 4);
    int*   deg_c  = (int*)  take((size_t)NN * 4);          // contiguous with deg_s (one memset)
    int*   deg_s  = (int*)  take((size_t)NN * 4);
    float* dinv_c = (float*)take((size_t)NN * 4);
    float* dinv_s = (float*)take((size_t)NN * 4);
    int*   offs_c = (int*)  take((size_t)(NN + 1) * 4);
    int*   offs_s = (int*)  take((size_t)(NN + 1) * 4);
    int*   rank_c = (int*)  take((size_t)NE * 4);
    int*   rank_s = (int*)  take((size_t)NE * 4);
    int*   csr_c  = (int*)  take((size_t)NE * 4);
    int*   csr_s  = (int*)  take((size_t)NE * 4);
    int*   bsum_c = (int*)  take((size_t)NB * 4);
    int*   bsum_s = (int*)  take((size_t)NB * 4);
    float* pool_c = (float*)take((size_t)NG * HD * 4);     // contiguous region: pool_c..cnt_s
    float* pool_s = (float*)take((size_t)NG * HD * 4);
    int*   cnt_c  = (int*)  take((size_t)NG * 4);
    int*   cnt_s  = (int*)  take((size_t)NG * 4);
    (void)ws_size; (void)in_sizes; (void)n_in; (void)out_size;

    hipMemsetAsync(deg_c, 0, (size_t)2 * NN * 4, stream);                       // deg_c + deg_s
    hipMemsetAsync(pool_c, 0, ((size_t)2 * NG * HD + 2 * NG) * 4, stream);      // pools + cnts

    const int* src_c = ei_c;           const int* dst_c = ei_c + NE;
    const int* src_s = ei_s;           const int* dst_s = ei_s + NE;

    k_hist  <<<(2 * NE + 255) / 256, 256, 0, stream>>>(dst_c, dst_s, batch_c, batch_s,
                                                       deg_c, deg_s, cnt_c, cnt_s,
                                                       rank_c, rank_s);
    k_scan1m<<<2 * NB, 256, 0, stream>>>(deg_c, deg_s, bsum_c, bsum_s, dinv_c, dinv_s,
                                         x_c, x_s, xs_c, xs_s);
    k_scan3m<<<2 * NB, 256, 0, stream>>>(deg_c, deg_s, bsum_c, bsum_s, offs_c, offs_s);
    k_fillm <<<(2 * NE + 255) / 256, 256, 0, stream>>>(src_c, dst_c, src_s, dst_s,
                                                       rank_c, rank_s, offs_c, offs_s,
                                                       csr_c, csr_s);
    k_aggxm <<<2 * NN * 8 / 256, 256, 0, stream>>>(xs_c, xs_s, dinv_c, dinv_s,
                                                   offs_c, offs_s, csr_c, csr_s, axd_c, axd_s);

    k_agp2<<<2 * NBT, 256, 0, stream>>>(axd_c, axd_s,
                                        offs_c, offs_s, csr_c, csr_s, batch_c, batch_s,
                                        Wc0, bc0, bnc_g, bnc_b, bnc_m, bnc_v, Wc1, bc1,
                                        Ws0, bs0, bns_g, bns_b, bns_m, bns_v, Ws1, bs1,
                                        pool_c, pool_s);

    k_mlp<<<NG / GPB, 128, 0, stream>>>(pool_c, pool_s, cnt_c, cnt_s,
                                        fc1_w, fc1_b, fc2_w, fc2_b, (float*)d_out);
}